// Round 10
// baseline (163.127 us; speedup 1.0000x reference)
//
#include <hip/hip_runtime.h>
#include <cstdint>
#include <cstddef>

#define S_LEN 2048
#define DMODEL 1024
#define NHEADS 16
#define DKH 64
#define MROWS 4096
#define BH_CNT 32

typedef __bf16 bf16x8 __attribute__((ext_vector_type(8)));
typedef __bf16 bf16x2 __attribute__((ext_vector_type(2)));
typedef float f32x4 __attribute__((ext_vector_type(4)));
typedef unsigned int u32x4 __attribute__((ext_vector_type(4)));
typedef unsigned int u32;
typedef unsigned short u16;

__device__ __forceinline__ u16 f2bfu(float f) {
  u32 u = __float_as_uint(f);
  return (u16)((u + 0x7FFFu + ((u >> 16) & 1u)) >> 16);
}

// compiler-cast bf16 pack (lowers to v_cvt_pk_bf16_f32 on gfx950)
__device__ __forceinline__ u32 pk_bf16(float a, float b) {
  bf16x2 v;
  v[0] = (__bf16)a;
  v[1] = (__bf16)b;
  return __builtin_bit_cast(u32, v);
}

// true-swap cross-lane ops (gfx950): both operands modified
__device__ __forceinline__ void pl32swap(u32& a, u32& b) {
#if __has_builtin(__builtin_amdgcn_permlane32_swap)
  auto r = __builtin_amdgcn_permlane32_swap((int)a, (int)b, false, false);
  a = (u32)r[0]; b = (u32)r[1];
#else
  asm volatile("v_permlane32_swap_b32 %0, %1" : "+v"(a), "+v"(b));
#endif
}
__device__ __forceinline__ void pl16swap(u32& a, u32& b) {
#if __has_builtin(__builtin_amdgcn_permlane16_swap)
  auto r = __builtin_amdgcn_permlane16_swap((int)a, (int)b, false, false);
  a = (u32)r[0]; b = (u32)r[1];
#else
  asm volatile("v_permlane16_swap_b32 %0, %1" : "+v"(a), "+v"(b));
#endif
}

__device__ __forceinline__ void gload16(void* lds, const void* g) {
  __builtin_amdgcn_global_load_lds(
      (const __attribute__((address_space(1))) void*)g,
      (__attribute__((address_space(3))) void*)lds, 16, 0, 0);
}

// wave-local counted wait on outstanding global_load_lds (rule #18: fence after)
#define WAITV(n)                                            \
  do {                                                      \
    asm volatile("s_waitcnt vmcnt(" #n ")" ::: "memory");   \
    __builtin_amdgcn_sched_barrier(0);                      \
  } while (0)

// ---------------- prep: x -> bf16 ----------------
__global__ __launch_bounds__(256) void prep_xb_k(const float* __restrict__ x,
                                                 u16* __restrict__ xb) {
  int i = (blockIdx.x * 256 + threadIdx.x) * 4;
  float4 v = *(const float4*)(x + i);
  *(uint2*)(xb + i) = make_uint2(pk_bf16(v.x, v.y), pk_bf16(v.z, v.w));
}

// ---------------- prep: W^T (n-major) bf16, K pre-scaled ----------------
// K scale folds 1/sqrt(dk)*phase AND 1/(2pi): scores arrive in REVOLUTIONS.
__global__ __launch_bounds__(256) void prep_w_k(const float* __restrict__ Wq,
    const float* __restrict__ Wk, const float* __restrict__ Wv,
    const float* __restrict__ ps, u16* __restrict__ Wb) {
  __shared__ float tile[32][33];
  int sel = blockIdx.z;
  const float* W = sel == 0 ? Wq : (sel == 1 ? Wk : Wv);
  int k0 = blockIdx.x * 32, c0 = blockIdx.y * 32;
  int tx = threadIdx.x, ty = threadIdx.y;
#pragma unroll
  for (int i = 0; i < 4; ++i)
    tile[ty + i * 8][tx] = W[(size_t)(k0 + ty + i * 8) * DMODEL + c0 + tx];
  __syncthreads();
#pragma unroll
  for (int i = 0; i < 4; ++i) {
    int row = ty + i * 8;
    float v = tile[tx][row];
    if (sel == 1) v *= 0.019894367886486918f * ps[(c0 + row) >> 6];  // 0.125/(2pi)
    Wb[(size_t)(sel * 1024 + c0 + row) * DMODEL + k0 + tx] = f2bfu(v);
  }
}

// ---------------- prep: Wo_eff[d][j] = sum_m (sum_h ent[h][m]) * Wo[m*64+d][j] ----------------
__global__ __launch_bounds__(256) void prep_woeff_k(const float* __restrict__ Wo,
    const float* __restrict__ ent, float* __restrict__ Woeff) {
  __shared__ float e[16];
  int t = threadIdx.x;
  if (t < 16) {
    float s = 0.f;
#pragma unroll
    for (int h = 0; h < 16; ++h) s += ent[h * 16 + t];
    e[t] = s;
  }
  __syncthreads();
  int gid = blockIdx.x * 256 + t;
  int d = gid >> 10, j = gid & 1023;
  float acc = 0.f;
#pragma unroll
  for (int m = 0; m < 16; ++m) acc += e[m] * Wo[(size_t)((m << 6) + d) * DMODEL + j];
  Woeff[(size_t)d * DMODEL + j] = acc;
}

// ---------------- QKV projection GEMM: [4096,1024] x [1024,3072] ----------------
// 128x128 tile, BK=32, double-buffered staging, one barrier per K-step.
// Grid: XCD-rectangle swizzle. Epilogue through LDS for coalesced stores.
__global__ __launch_bounds__(256) void gemm_qkv_k(const u16* __restrict__ xb,
    const u16* __restrict__ Wb, u16* __restrict__ Qb, u16* __restrict__ Kb,
    u16* __restrict__ Vt) {
  __shared__ __align__(16) u16 SMEM[2][2][128 * 32];  // [A/B][dbuf][tile]
  int bid = blockIdx.x;
  int xcd = bid & 7, wi = bid >> 3;
  int mg = xcd >> 1, ng = xcd & 1;
  int mt = mg * 8 + (wi & 7);
  int nt = ng * 12 + (wi >> 3);
  int m0 = mt * 128, n0 = nt * 128;
  int tid = threadIdx.x;
  int lane = tid & 63, w = tid >> 6;
  int c = lane & 15, g = lane >> 4;
  int wr = w >> 1, wc = w & 1;

  int cij0 = (w * 2) * 64 + lane, cij1 = (w * 2 + 1) * 64 + lane;
  int row0 = cij0 >> 2, kp0 = (cij0 & 3) ^ (row0 & 3);
  int row1 = cij1 >> 2, kp1 = (cij1 & 3) ^ (row1 & 3);
  const u16* a0p = xb + (size_t)(m0 + row0) * DMODEL + kp0 * 8;
  const u16* a1p = xb + (size_t)(m0 + row1) * DMODEL + kp1 * 8;
  const u16* b0p = Wb + (size_t)(n0 + row0) * DMODEL + kp0 * 8;
  const u16* b1p = Wb + (size_t)(n0 + row1) * DMODEL + kp1 * 8;

  f32x4 acc[4][4];
#pragma unroll
  for (int i = 0; i < 4; ++i)
#pragma unroll
    for (int j = 0; j < 4; ++j) acc[i][j] = (f32x4){0.f, 0.f, 0.f, 0.f};

  // prologue stage
  gload16(&SMEM[0][0][(w * 2) * 512], a0p);
  gload16(&SMEM[0][0][(w * 2 + 1) * 512], a1p);
  gload16(&SMEM[1][0][(w * 2) * 512], b0p);
  gload16(&SMEM[1][0][(w * 2 + 1) * 512], b1p);
  __syncthreads();

  int cur = 0;
  for (int kt = 0; kt < DMODEL; kt += 32) {
    if (kt + 32 < DMODEL) {
      int nx = cur ^ 1, ko = kt + 32;
      gload16(&SMEM[0][nx][(w * 2) * 512], a0p + ko);
      gload16(&SMEM[0][nx][(w * 2 + 1) * 512], a1p + ko);
      gload16(&SMEM[1][nx][(w * 2) * 512], b0p + ko);
      gload16(&SMEM[1][nx][(w * 2 + 1) * 512], b1p + ko);
    }
    const u16* Ac = SMEM[0][cur];
    const u16* Bc = SMEM[1][cur];
    bf16x8 af[4], bf[4];
#pragma unroll
    for (int i = 0; i < 4; ++i) {
      int ra = wr * 64 + i * 16 + c;
      af[i] = *(const bf16x8*)(Ac + ra * 32 + ((g ^ (ra & 3)) * 8));
      int rb = wc * 64 + i * 16 + c;
      bf[i] = *(const bf16x8*)(Bc + rb * 32 + ((g ^ (rb & 3)) * 8));
    }
#pragma unroll
    for (int i = 0; i < 4; ++i)
#pragma unroll
      for (int j = 0; j < 4; ++j)
        acc[i][j] = __builtin_amdgcn_mfma_f32_16x16x32_bf16(af[i], bf[j], acc[i][j], 0, 0, 0);
    __syncthreads();
    cur ^= 1;
  }

  // ---- epilogue via LDS (reuse staging buffers: 32KB = 128x128 u16) ----
  int sel = n0 >> 10;
  char* Ls = (char*)&SMEM[0][0][0];
  if (sel == 2) {
    // LDS layout transposed: row = n-local (d), col = m-local (s)
#pragma unroll
    for (int i = 0; i < 4; ++i)
#pragma unroll
      for (int jf = 0; jf < 4; ++jf) {
        int n = wc * 64 + jf * 16 + c;
        int m = wr * 64 + i * 16 + 4 * g;
        int byte = n * 256 + ((m * 2) ^ ((n & 7) << 4));
        *(uint2*)(Ls + byte) = make_uint2(pk_bf16(acc[i][jf][0], acc[i][jf][1]),
                                          pk_bf16(acc[i][jf][2], acc[i][jf][3]));
      }
  } else {
    // LDS layout: row = m-local (s), col = n-local (d)
#pragma unroll
    for (int i = 0; i < 4; ++i)
#pragma unroll
      for (int jf = 0; jf < 4; ++jf) {
        int n = wc * 64 + jf * 16 + c;
#pragma unroll
        for (int j = 0; j < 4; ++j) {
          int m = wr * 64 + i * 16 + 4 * g + j;
          int byte = m * 256 + ((n * 2) ^ ((m & 7) << 4));
          __bf16 hv = (__bf16)acc[i][jf][j];
          *(u16*)(Ls + byte) = __builtin_bit_cast(u16, hv);
        }
      }
  }
  __syncthreads();
  int r = tid >> 1, half = tid & 1;
  int h0 = (n0 & 1023) >> 6;
  int b = m0 >> 11, sbase = m0 & 2047;
  u16* dst;
  if (sel == 2) {
    int bh = b * 16 + h0 + (r >> 6), d = r & 63;
    dst = Vt + ((size_t)bh * DKH + d) * S_LEN + sbase + half * 64;
  } else {
    u16* base = (sel == 0 ? Qb : Kb);
    int bh = b * 16 + h0 + half;
    dst = base + ((size_t)bh * S_LEN + sbase + r) * DKH;
  }
#pragma unroll
  for (int kk = 0; kk < 8; ++kk) {
    int byte = r * 256 + ((half * 128 + kk * 16) ^ ((r & 7) << 4));
    *(uint4*)(dst + kk * 8) = *(const uint4*)(Ls + byte);
  }
}

// ---------------- fused cos-softmax flash attention (barrier-free main loop) ----------------
// 4 waves = 4 k-quarters, each covering the block's 32 q-rows. Wave-PRIVATE
// K/V staging (2KB K + 2KB V per tile, double-buffered) -> zero staging
// redundancy and NO __syncthreads in the main loop; sync is per-wave counted
// s_waitcnt vmcnt(4)/(0). PV every 2 tiles: (tileE,tileO) P-words feed the
// round-7-verified pl32/pl16 swap recipe -> B-fragment k=8g..8g+7. Denominator
// via ones-row MFMA. In-register softmax (v_cos + 2 fma + v_exp2, scores in
// revolutions). 3-barrier epilogue tree-combines the 4 k-partials.
__global__ __launch_bounds__(256) void attn_k(const u16* __restrict__ Qb,
    const u16* __restrict__ Kb, const u16* __restrict__ Vt,
    float* __restrict__ attbuf) {
  __shared__ __align__(16) u16 PRIV[4][4][1024];  // [wave][KA,KB,VA,VB][2KB]
  __shared__ float dred[4][2][16];
  int fid = blockIdx.x;
  int swz = (fid & 7) * 256 + (fid >> 3);  // 2048 blocks, 8 XCDs -> bijective; 4 heads/XCD
  int bh = swz >> 6, qblk = swz & 63;
  int tid = threadIdx.x;
  int lane = tid & 63, w = tid >> 6;
  int c = lane & 15, g = lane >> 4;
  int q0 = qblk * 32;
  const float L2E = 1.4426950408889634f;

  // wave's k-quarter bases
  const u16* Kqb = Kb + (size_t)bh * S_LEN * DKH + (size_t)(w * 16) * DKH;
  const u16* Vqb = Vt + (size_t)bh * DKH * S_LEN + (w * 16);

  // staging source per-lane addresses (K pre-swizzled: slot s holds chunk s^(r&7))
  int rA = lane >> 3, sA = lane & 7;
  const u16* KsrcA = Kqb + (size_t)rA * DKH + ((sA ^ (rA & 7)) * 8);
  const u16* KsrcB = Kqb + (size_t)(rA + 8) * DKH + ((sA ^ ((rA + 8) & 7)) * 8);
  int dA = lane >> 1, hA = lane & 1;
  const u16* VsrcA = Vqb + (size_t)dA * S_LEN + hA * 8;
  const u16* VsrcB = Vqb + (size_t)(dA + 32) * S_LEN + hA * 8;

  u16* KL = &PRIV[w][0][0];  // KA at +0, KB at +1024
  u16* VL = &PRIV[w][2][0];  // VA at +0, VB at +1024

  auto stage = [&](int buf, int tile) {
    size_t ko = (size_t)tile * 64 * DKH;
    int vo = tile * 64;
    gload16(KL + buf * 1024, KsrcA + ko);
    gload16(KL + buf * 1024 + 512, KsrcB + ko);
    gload16(VL + buf * 1024, VsrcA + vo);
    gload16(VL + buf * 1024 + 512, VsrcB + vo);
  };

  // Q fragments (2 q-groups x 2 dk-halves)
  bf16x8 qf[2][2];
#pragma unroll
  for (int qg = 0; qg < 2; ++qg) {
    const u16* qp = Qb + ((size_t)bh * S_LEN + q0 + qg * 16 + c) * DKH + g * 8;
    qf[qg][0] = *(const bf16x8*)qp;
    qf[qg][1] = *(const bf16x8*)(qp + 32);
  }
  bf16x8 onesf;
#pragma unroll
  for (int i = 0; i < 8; ++i) onesf[i] = (__bf16)1.0f;

  // LDS read offsets (u16 units)
  int kr0 = c * 64 + ((g ^ (c & 7)) * 8);
  int kr1 = c * 64 + (((4 + g) ^ (c & 7)) * 8);
  int vrb = (g >> 1) * 1024 + c * 16 + (g & 1) * 8;  // + fd*256

  f32x4 attT[4][2];
#pragma unroll
  for (int i = 0; i < 4; ++i)
#pragma unroll
    for (int qg = 0; qg < 2; ++qg) attT[i][qg] = (f32x4){0.f, 0.f, 0.f, 0.f};
  f32x4 denacc[2];
  denacc[0] = (f32x4){0.f, 0.f, 0.f, 0.f};
  denacc[1] = (f32x4){0.f, 0.f, 0.f, 0.f};

  int rot = (qblk & 15) * 2;  // even rotation keeps pair structure
  stage(0, rot);              // prologue: pair-even tile into buf0

  for (int p = 0; p < 16; ++p) {
    int e = (2 * p + rot) & 31;
    stage(1, e + 1);  // odd tile of the pair into buf1
    WAITV(4);         // buf0 (even tile) ready; buf1's 4 still in flight

    f32x4 sTE[2];
#pragma unroll
    for (int qg = 0; qg < 2; ++qg) {
      bf16x8 ka = *(const bf16x8*)(KL + kr0);
      bf16x8 kb2 = *(const bf16x8*)(KL + kr1);
      f32x4 z = (f32x4){0.f, 0.f, 0.f, 0.f};
      z = __builtin_amdgcn_mfma_f32_16x16x32_bf16(ka, qf[qg][0], z, 0, 0, 0);
      sTE[qg] = __builtin_amdgcn_mfma_f32_16x16x32_bf16(kb2, qf[qg][1], z, 0, 0, 0);
    }
    u32 wqE[2][2];
#pragma unroll
    for (int qg = 0; qg < 2; ++qg) {
      float pv[4];
#pragma unroll
      for (int j = 0; j < 4; ++j) {
        float cv = __builtin_amdgcn_cosf(sTE[qg][j]);  // revolutions
        float w2 = __fmaf_rn(cv, __fmaf_rn(0.2f * L2E, cv, L2E), -0.1f * L2E);
        pv[j] = __builtin_amdgcn_exp2f(w2);
      }
      wqE[qg][0] = pk_bf16(pv[0], pv[1]);
      wqE[qg][1] = pk_bf16(pv[2], pv[3]);
    }

    WAITV(0);  // buf1 (odd tile) ready
    f32x4 sTO[2];
#pragma unroll
    for (int qg = 0; qg < 2; ++qg) {
      bf16x8 ka = *(const bf16x8*)(KL + 1024 + kr0);
      bf16x8 kb2 = *(const bf16x8*)(KL + 1024 + kr1);
      f32x4 z = (f32x4){0.f, 0.f, 0.f, 0.f};
      z = __builtin_amdgcn_mfma_f32_16x16x32_bf16(ka, qf[qg][0], z, 0, 0, 0);
      sTO[qg] = __builtin_amdgcn_mfma_f32_16x16x32_bf16(kb2, qf[qg][1], z, 0, 0, 0);
    }
    u32 wqO[2][2];
#pragma unroll
    for (int qg = 0; qg < 2; ++qg) {
      float pv[4];
#pragma unroll
      for (int j = 0; j < 4; ++j) {
        float cv = __builtin_amdgcn_cosf(sTO[qg][j]);
        float w2 = __fmaf_rn(cv, __fmaf_rn(0.2f * L2E, cv, L2E), -0.1f * L2E);
        pv[j] = __builtin_amdgcn_exp2f(w2);
      }
      wqO[qg][0] = pk_bf16(pv[0], pv[1]);
      wqO[qg][1] = pk_bf16(pv[2], pv[3]);
    }

    // (E,O) -> PV B-fragment via the round-7-verified swap recipe
    bf16x8 pf[2];
#pragma unroll
    for (int qg = 0; qg < 2; ++qg) {
      u32 b0 = wqE[qg][0], b2 = wqO[qg][0];
      pl32swap(b0, b2);
      pl16swap(b0, b2);
      u32 b1 = wqE[qg][1], b3 = wqO[qg][1];
      pl32swap(b1, b3);
      pl16swap(b1, b3);
      pf[qg] = __builtin_bit_cast(bf16x8, (u32x4){b0, b1, b2, b3});
    }

    __builtin_amdgcn_s_setprio(1);
#pragma unroll
    for (int fd = 0; fd < 4; ++fd) {
      bf16x8 vf = *(const bf16x8*)(VL + vrb + fd * 256);
#pragma unroll
      for (int qg = 0; qg < 2; ++qg)
        attT[fd][qg] = __builtin_amdgcn_mfma_f32_16x16x32_bf16(vf, pf[qg], attT[fd][qg], 0, 0, 0);
    }
#pragma unroll
    for (int qg = 0; qg < 2; ++qg)
      denacc[qg] = __builtin_amdgcn_mfma_f32_16x16x32_bf16(onesf, pf[qg], denacc[qg], 0, 0, 0);
    __builtin_amdgcn_s_setprio(0);

    if (p < 15) stage(0, (e + 2) & 31);  // next even tile (V-A consumed)
  }

  // ---- epilogue: tree-combine the 4 k-quarter partials ----
  if (g == 0) {
    dred[w][0][c] = denacc[0][0];
    dred[w][1][c] = denacc[1][0];
  }
  __syncthreads();  // main-loop LDS fully retired before reuse
  float* R = (float*)&PRIV[0][0][0];  // 2 regions x 8KB (waves 0,1 areas)
  if (w >= 2) {
    float* Rq = R + (w - 2) * 2048;
#pragma unroll
    for (int fd = 0; fd < 4; ++fd)
#pragma unroll
      for (int qg = 0; qg < 2; ++qg)
        *(f32x4*)&Rq[(qg * 16 + c) * 64 + fd * 16 + 4 * g] = attT[fd][qg];
  }
  __syncthreads();
  if (w < 2) {
    float* Rq = R + w * 2048;
#pragma unroll
    for (int fd = 0; fd < 4; ++fd)
#pragma unroll
      for (int qg = 0; qg < 2; ++qg)
        attT[fd][qg] += *(const f32x4*)&Rq[(qg * 16 + c) * 64 + fd * 16 + 4 * g];
  }
  if (w == 1) {
    float* Rq = R + 2048;
#pragma unroll
    for (int fd = 0; fd < 4; ++fd)
#pragma unroll
      for (int qg = 0; qg < 2; ++qg)
        *(f32x4*)&Rq[(qg * 16 + c) * 64 + fd * 16 + 4 * g] = attT[fd][qg];
  }
  __syncthreads();
  if (w == 0) {
    float inv[2];
#pragma unroll
    for (int qg = 0; qg < 2; ++qg)
      inv[qg] = 1.f / (dred[0][qg][c] + dred[1][qg][c] + dred[2][qg][c] + dred[3][qg][c]);
    float* Rq = R + 2048;
#pragma unroll
    for (int fd = 0; fd < 4; ++fd)
#pragma unroll
      for (int qg = 0; qg < 2; ++qg) {
        f32x4 part = *(const f32x4*)&Rq[(qg * 16 + c) * 64 + fd * 16 + 4 * g];
        f32x4 tot = (attT[fd][qg] + part) * inv[qg];
        int q = q0 + qg * 16 + c;
        *(f32x4*)(attbuf + ((size_t)bh * S_LEN + q) * DKH + fd * 16 + 4 * g) = tot;
      }
  }
}

// ---------------- head-reduce + a@Wo_eff + bias + residual + LayerNorm ----------------
__global__ __launch_bounds__(256) void fuse_out_ln_k(const float* __restrict__ attbuf,
    const float* __restrict__ Woeff, const float* __restrict__ bo,
    const float* __restrict__ x, const float* __restrict__ gamma,
    const float* __restrict__ beta, float* __restrict__ out) {
  __shared__ float red[8][256];
  __shared__ __align__(16) float a[8][64];
  __shared__ float sred[8][4][2];
  int t = threadIdx.x;
  int r0 = blockIdx.x * 8;
  int d = t & 63, hg = t >> 6;
#pragma unroll
  for (int rr = 0; rr < 8; ++rr) {
    int m = r0 + rr, b = m >> 11, sr = m & 2047;
    float pa = 0.f;
#pragma unroll
    for (int hh = 0; hh < 4; ++hh) {
      int h = hg * 4 + hh;
      pa += attbuf[(((size_t)(b * 16 + h)) * S_LEN + sr) * DKH + d];
    }
    red[rr][t] = pa;
  }
  __syncthreads();
#pragma unroll
  for (int e = 0; e < 2; ++e) {
    int idx = t + e * 256;
    int rr = idx >> 6, dd = idx & 63;
    a[rr][dd] = red[rr][dd] + red[rr][64 + dd] + red[rr][128 + dd] + red[rr][192 + dd];
  }
  __syncthreads();

  float o[8][4];
#pragma unroll
  for (int rr = 0; rr < 8; ++rr) { o[rr][0] = o[rr][1] = o[rr][2] = o[rr][3] = 0.f; }
  int c4 = t * 4;
  for (int dd = 0; dd < 64; dd += 4) {
    float4 wv0 = *(const float4*)(Woeff + (size_t)(dd + 0) * DMODEL + c4);
    float4 wv1 = *(const float4*)(Woeff + (size_t)(dd + 1) * DMODEL + c4);
    float4 wv2 = *(const float4*)(Woeff + (size_t)(dd + 2) * DMODEL + c4);
    float4 wv3 = *(const float4*)(Woeff + (size_t)(dd + 3) * DMODEL + c4);
#pragma unroll
    for (int rr = 0; rr < 8; ++rr) {
      float4 av = *(const float4*)&a[rr][dd];
      o[rr][0] += av.x * wv0.x + av.y * wv1.x + av.z * wv2.x + av.w * wv3.x;
      o[rr][1] += av.x * wv0.y + av.y * wv1.y + av.z * wv2.y + av.w * wv3.y;
      o[rr][2] += av.x * wv0.z + av.y * wv1.z + av.z * wv2.z + av.w * wv3.z;
      o[rr][3] += av.x * wv0.w + av.y * wv1.w + av.z * wv2.w + av.w * wv3.w;
    }
  }
  float4 bv = *(const float4*)(bo + c4);
  int w = t >> 6, lane = t & 63;
#pragma unroll
  for (int rr = 0; rr < 8; ++rr) {
    int m = r0 + rr;
    float4 xv = *(const float4*)(x + (size_t)m * DMODEL + c4);
    o[rr][0] += bv.x + xv.x;
    o[rr][1] += bv.y + xv.y;
    o[rr][2] += bv.z + xv.z;
    o[rr][3] += bv.w + xv.w;
    float s = o[rr][0] + o[rr][1] + o[rr][2] + o[rr][3];
    float q = o[rr][0] * o[rr][0] + o[rr][1] * o[rr][1] + o[rr][2] * o[rr][2] + o[rr][3] * o[rr][3];
#pragma unroll
    for (int mm = 1; mm < 64; mm <<= 1) {
      s += __shfl_xor(s, mm, 64);
      q += __shfl_xor(q, mm, 64);
    }
    if (lane == 0) { sred[rr][w][0] = s; sred[rr][w][1] = q; }
  }
  __syncthreads();
  float4 gv = *(const float4*)(gamma + c4);
  float4 bev = *(const float4*)(beta + c4);
#pragma unroll
  for (int rr = 0; rr < 8; ++rr) {
    float s = sred[rr][0][0] + sred[rr][1][0] + sred[rr][2][0] + sred[rr][3][0];
    float q = sred[rr][0][1] + sred[rr][1][1] + sred[rr][2][1] + sred[rr][3][1];
    float mu = s * (1.f / 1024.f);
    float var = q * (1.f / 1024.f) - mu * mu;
    float rs = rsqrtf(var + 1e-6f);
    int m = r0 + rr;
    float4 ov;
    ov.x = gv.x * (o[rr][0] - mu) * rs + bev.x;
    ov.y = gv.y * (o[rr][1] - mu) * rs + bev.y;
    ov.z = gv.z * (o[rr][2] - mu) * rs + bev.z;
    ov.w = gv.w * (o[rr][3] - mu) * rs + bev.w;
    *(float4*)(out + (size_t)m * DMODEL + c4) = ov;
  }
}

extern "C" void kernel_launch(void* const* d_in, const int* in_sizes, int n_in,
                              void* d_out, int out_size, void* d_ws, size_t ws_size,
                              hipStream_t stream) {
  const float* x = (const float*)d_in[0];
  const float* Wq = (const float*)d_in[1];
  const float* Wk = (const float*)d_in[2];
  const float* Wv = (const float*)d_in[3];
  const float* Wo = (const float*)d_in[4];
  const float* bo = (const float*)d_in[5];
  const float* ps = (const float*)d_in[6];
  const float* ent = (const float*)d_in[7];
  const float* gamma = (const float*)d_in[8];
  const float* beta = (const float*)d_in[9];
  float* out = (float*)d_out;

  char* ws = (char*)d_ws;
  size_t o = 0;
  u16* xb = (u16*)(ws + o);    o += (size_t)MROWS * DMODEL * 2;        // 8 MB
  u16* Wb = (u16*)(ws + o);    o += (size_t)3072 * 1024 * 2;           // 6 MB
  u16* Qb = (u16*)(ws + o);    o += (size_t)BH_CNT * S_LEN * DKH * 2;  // 8 MB
  u16* Kb = (u16*)(ws + o);    o += (size_t)BH_CNT * S_LEN * DKH * 2;  // 8 MB
  u16* Vt = (u16*)(ws + o);    o += (size_t)BH_CNT * S_LEN * DKH * 2;  // 8 MB
  float* Woeff = (float*)(ws + o);  o += (size_t)DKH * DMODEL * 4;     // 256 KB
  float* attbuf = (float*)(ws + o); o += (size_t)BH_CNT * S_LEN * DKH * 4;  // 16 MB

  prep_xb_k<<<dim3(4096), dim3(256), 0, stream>>>(x, xb);
  prep_w_k<<<dim3(32, 32, 3), dim3(32, 8), 0, stream>>>(Wq, Wk, Wv, ps, Wb);
  prep_woeff_k<<<dim3(256), dim3(256), 0, stream>>>(Wo, ent, Woeff);
  gemm_qkv_k<<<dim3(768), dim3(256), 0, stream>>>(xb, Wb, Qb, Kb, Vt);
  attn_k<<<dim3(2048), dim3(256), 0, stream>>>(Qb, Kb, Vt, attbuf);
  fuse_out_ln_k<<<dim3(512), dim3(256), 0, stream>>>(attbuf, Woeff, bo, x, gamma, beta, out);
}

// Round 11
// 128.993 us; speedup vs baseline: 1.2646x; 1.2646x over previous
//
#include <hip/hip_runtime.h>
#include <cstdint>
#include <cstddef>

#define S_LEN 2048
#define DMODEL 1024
#define NHEADS 16
#define DKH 64
#define MROWS 4096
#define BH_CNT 32

typedef __bf16 bf16x8 __attribute__((ext_vector_type(8)));
typedef __bf16 bf16x2 __attribute__((ext_vector_type(2)));
typedef float f32x4 __attribute__((ext_vector_type(4)));
typedef unsigned int u32x4 __attribute__((ext_vector_type(4)));
typedef unsigned int u32;
typedef unsigned short u16;

__device__ __forceinline__ u16 f2bfu(float f) {
  u32 u = __float_as_uint(f);
  return (u16)((u + 0x7FFFu + ((u >> 16) & 1u)) >> 16);
}

// compiler-cast bf16 pack (lowers to v_cvt_pk_bf16_f32 on gfx950)
__device__ __forceinline__ u32 pk_bf16(float a, float b) {
  bf16x2 v;
  v[0] = (__bf16)a;
  v[1] = (__bf16)b;
  return __builtin_bit_cast(u32, v);
}

// true-swap cross-lane ops (gfx950): both operands modified
__device__ __forceinline__ void pl32swap(u32& a, u32& b) {
#if __has_builtin(__builtin_amdgcn_permlane32_swap)
  auto r = __builtin_amdgcn_permlane32_swap((int)a, (int)b, false, false);
  a = (u32)r[0]; b = (u32)r[1];
#else
  asm volatile("v_permlane32_swap_b32 %0, %1" : "+v"(a), "+v"(b));
#endif
}
__device__ __forceinline__ void pl16swap(u32& a, u32& b) {
#if __has_builtin(__builtin_amdgcn_permlane16_swap)
  auto r = __builtin_amdgcn_permlane16_swap((int)a, (int)b, false, false);
  a = (u32)r[0]; b = (u32)r[1];
#else
  asm volatile("v_permlane16_swap_b32 %0, %1" : "+v"(a), "+v"(b));
#endif
}

__device__ __forceinline__ void gload16(void* lds, const void* g) {
  __builtin_amdgcn_global_load_lds(
      (const __attribute__((address_space(1))) void*)g,
      (__attribute__((address_space(3))) void*)lds, 16, 0, 0);
}

// ---------------- prep: x -> bf16 ----------------
__global__ __launch_bounds__(256) void prep_xb_k(const float* __restrict__ x,
                                                 u16* __restrict__ xb) {
  int i = (blockIdx.x * 256 + threadIdx.x) * 4;
  float4 v = *(const float4*)(x + i);
  *(uint2*)(xb + i) = make_uint2(pk_bf16(v.x, v.y), pk_bf16(v.z, v.w));
}

// ---------------- prep: W^T (n-major) bf16, K pre-scaled ----------------
// K scale folds 1/sqrt(dk)*phase AND 1/(2pi): scores arrive in REVOLUTIONS.
__global__ __launch_bounds__(256) void prep_w_k(const float* __restrict__ Wq,
    const float* __restrict__ Wk, const float* __restrict__ Wv,
    const float* __restrict__ ps, u16* __restrict__ Wb) {
  __shared__ float tile[32][33];
  int sel = blockIdx.z;
  const float* W = sel == 0 ? Wq : (sel == 1 ? Wk : Wv);
  int k0 = blockIdx.x * 32, c0 = blockIdx.y * 32;
  int tx = threadIdx.x, ty = threadIdx.y;
#pragma unroll
  for (int i = 0; i < 4; ++i)
    tile[ty + i * 8][tx] = W[(size_t)(k0 + ty + i * 8) * DMODEL + c0 + tx];
  __syncthreads();
#pragma unroll
  for (int i = 0; i < 4; ++i) {
    int row = ty + i * 8;
    float v = tile[tx][row];
    if (sel == 1) v *= 0.019894367886486918f * ps[(c0 + row) >> 6];  // 0.125/(2pi)
    Wb[(size_t)(sel * 1024 + c0 + row) * DMODEL + k0 + tx] = f2bfu(v);
  }
}

// ---------------- prep: Wo_eff[d][j] = sum_m (sum_h ent[h][m]) * Wo[m*64+d][j] ----------------
__global__ __launch_bounds__(256) void prep_woeff_k(const float* __restrict__ Wo,
    const float* __restrict__ ent, float* __restrict__ Woeff) {
  __shared__ float e[16];
  int t = threadIdx.x;
  if (t < 16) {
    float s = 0.f;
#pragma unroll
    for (int h = 0; h < 16; ++h) s += ent[h * 16 + t];
    e[t] = s;
  }
  __syncthreads();
  int gid = blockIdx.x * 256 + t;
  int d = gid >> 10, j = gid & 1023;
  float acc = 0.f;
#pragma unroll
  for (int m = 0; m < 16; ++m) acc += e[m] * Wo[(size_t)((m << 6) + d) * DMODEL + j];
  Woeff[(size_t)d * DMODEL + j] = acc;
}

// ---------------- QKV projection GEMM: [4096,1024] x [1024,3072] ----------------
// 128x128 tile, BK=32, double-buffered staging, one barrier per K-step.
// Grid: XCD-rectangle swizzle. Epilogue through LDS for coalesced stores.
__global__ __launch_bounds__(256) void gemm_qkv_k(const u16* __restrict__ xb,
    const u16* __restrict__ Wb, u16* __restrict__ Qb, u16* __restrict__ Kb,
    u16* __restrict__ Vt) {
  __shared__ __align__(16) u16 SMEM[2][2][128 * 32];  // [A/B][dbuf][tile]
  int bid = blockIdx.x;
  int xcd = bid & 7, wi = bid >> 3;
  int mg = xcd >> 1, ng = xcd & 1;
  int mt = mg * 8 + (wi & 7);
  int nt = ng * 12 + (wi >> 3);
  int m0 = mt * 128, n0 = nt * 128;
  int tid = threadIdx.x;
  int lane = tid & 63, w = tid >> 6;
  int c = lane & 15, g = lane >> 4;
  int wr = w >> 1, wc = w & 1;

  int cij0 = (w * 2) * 64 + lane, cij1 = (w * 2 + 1) * 64 + lane;
  int row0 = cij0 >> 2, kp0 = (cij0 & 3) ^ (row0 & 3);
  int row1 = cij1 >> 2, kp1 = (cij1 & 3) ^ (row1 & 3);
  const u16* a0p = xb + (size_t)(m0 + row0) * DMODEL + kp0 * 8;
  const u16* a1p = xb + (size_t)(m0 + row1) * DMODEL + kp1 * 8;
  const u16* b0p = Wb + (size_t)(n0 + row0) * DMODEL + kp0 * 8;
  const u16* b1p = Wb + (size_t)(n0 + row1) * DMODEL + kp1 * 8;

  f32x4 acc[4][4];
#pragma unroll
  for (int i = 0; i < 4; ++i)
#pragma unroll
    for (int j = 0; j < 4; ++j) acc[i][j] = (f32x4){0.f, 0.f, 0.f, 0.f};

  // prologue stage
  gload16(&SMEM[0][0][(w * 2) * 512], a0p);
  gload16(&SMEM[0][0][(w * 2 + 1) * 512], a1p);
  gload16(&SMEM[1][0][(w * 2) * 512], b0p);
  gload16(&SMEM[1][0][(w * 2 + 1) * 512], b1p);
  __syncthreads();

  int cur = 0;
  for (int kt = 0; kt < DMODEL; kt += 32) {
    if (kt + 32 < DMODEL) {
      int nx = cur ^ 1, ko = kt + 32;
      gload16(&SMEM[0][nx][(w * 2) * 512], a0p + ko);
      gload16(&SMEM[0][nx][(w * 2 + 1) * 512], a1p + ko);
      gload16(&SMEM[1][nx][(w * 2) * 512], b0p + ko);
      gload16(&SMEM[1][nx][(w * 2 + 1) * 512], b1p + ko);
    }
    const u16* Ac = SMEM[0][cur];
    const u16* Bc = SMEM[1][cur];
    bf16x8 af[4], bf[4];
#pragma unroll
    for (int i = 0; i < 4; ++i) {
      int ra = wr * 64 + i * 16 + c;
      af[i] = *(const bf16x8*)(Ac + ra * 32 + ((g ^ (ra & 3)) * 8));
      int rb = wc * 64 + i * 16 + c;
      bf[i] = *(const bf16x8*)(Bc + rb * 32 + ((g ^ (rb & 3)) * 8));
    }
#pragma unroll
    for (int i = 0; i < 4; ++i)
#pragma unroll
      for (int j = 0; j < 4; ++j)
        acc[i][j] = __builtin_amdgcn_mfma_f32_16x16x32_bf16(af[i], bf[j], acc[i][j], 0, 0, 0);
    __syncthreads();
    cur ^= 1;
  }

  // ---- epilogue via LDS (reuse staging buffers: 32KB = 128x128 u16) ----
  int sel = n0 >> 10;
  char* Ls = (char*)&SMEM[0][0][0];
  if (sel == 2) {
    // LDS layout transposed: row = n-local (d), col = m-local (s)
#pragma unroll
    for (int i = 0; i < 4; ++i)
#pragma unroll
      for (int jf = 0; jf < 4; ++jf) {
        int n = wc * 64 + jf * 16 + c;
        int m = wr * 64 + i * 16 + 4 * g;
        int byte = n * 256 + ((m * 2) ^ ((n & 7) << 4));
        *(uint2*)(Ls + byte) = make_uint2(pk_bf16(acc[i][jf][0], acc[i][jf][1]),
                                          pk_bf16(acc[i][jf][2], acc[i][jf][3]));
      }
  } else {
    // LDS layout: row = m-local (s), col = n-local (d)
#pragma unroll
    for (int i = 0; i < 4; ++i)
#pragma unroll
      for (int jf = 0; jf < 4; ++jf) {
        int n = wc * 64 + jf * 16 + c;
#pragma unroll
        for (int j = 0; j < 4; ++j) {
          int m = wr * 64 + i * 16 + 4 * g + j;
          int byte = m * 256 + ((n * 2) ^ ((m & 7) << 4));
          __bf16 hv = (__bf16)acc[i][jf][j];
          *(u16*)(Ls + byte) = __builtin_bit_cast(u16, hv);
        }
      }
  }
  __syncthreads();
  int r = tid >> 1, half = tid & 1;
  int h0 = (n0 & 1023) >> 6;
  int b = m0 >> 11, sbase = m0 & 2047;
  u16* dst;
  if (sel == 2) {
    int bh = b * 16 + h0 + (r >> 6), d = r & 63;
    dst = Vt + ((size_t)bh * DKH + d) * S_LEN + sbase + half * 64;
  } else {
    u16* base = (sel == 0 ? Qb : Kb);
    int bh = b * 16 + h0 + half;
    dst = base + ((size_t)bh * S_LEN + sbase + r) * DKH;
  }
#pragma unroll
  for (int kk = 0; kk < 8; ++kk) {
    int byte = r * 256 + ((half * 128 + kk * 16) ^ ((r & 7) << 4));
    *(uint4*)(dst + kk * 8) = *(const uint4*)(Ls + byte);
  }
}

// ---------------- fused cos-softmax flash attention ----------------
// 8 waves / 512 threads: waves = (grp q-half-of-128) x (h k-half) x (qh
// q-quarter). ONE shared K/V staged tile serves 128 q-rows -> per-CU
// staging DMA and issue HALVE vs the 4-wave/64q version; each wave issues
// just 2 gload16 per tile. Compute recipe identical to the verified round-7
// kernel: S^T = mfma(K,Q); in-register softmax (v_cos + 2 fma + v_exp2,
// scores in revolutions); permlane32/16 swaps move P into the PV B-fragment;
// denominator via ones-row MFMA. Per-group epilogue combines h-partners
// through the retired 32KB staging LDS (4 disjoint 8KB regions).
__global__ __launch_bounds__(512) void attn_k(const u16* __restrict__ Qb,
    const u16* __restrict__ Kb, const u16* __restrict__ Vt,
    float* __restrict__ attbuf) {
  __shared__ __align__(16) u16 Ks[2][4096];  // [dbuf][64x64] = 16KB
  __shared__ __align__(16) u16 Vs[2][4096];  // [dbuf][64x64] = 16KB
  __shared__ float dred[8][2][16];
  int fid = blockIdx.x;
  int swz = (fid & 7) * 64 + (fid >> 3);  // 512 blocks, 8 XCDs -> bijective
  int bh = swz >> 4, qb = swz & 15;       // 4 heads per XCD (K/V 2MB L2-resident)
  int tid = threadIdx.x;
  int lane = tid & 63, w = tid >> 6;
  int c = lane & 15, g = lane >> 4;
  int grp = w >> 2, h = (w >> 1) & 1, qh = w & 1;
  int q0 = qb * 128 + grp * 64;
  const float L2E = 1.4426950408889634f;

  const u16* Kbase = Kb + (size_t)bh * S_LEN * DKH;
  const u16* Vbase = Vt + (size_t)bh * DKH * S_LEN;

  // staging: wave w stages chunk w (512 u16) of Ks and Vs (pre-swizzled src)
  int srow = w * 8 + (lane >> 3), slot = lane & 7, kp = slot ^ (srow & 7);
  const u16* kSrc = Kbase + (size_t)srow * DKH + kp * 8;
  const u16* vSrc = Vbase + (size_t)srow * S_LEN + kp * 8;
  auto stage = [&](int buf, int tile) {
    gload16(&Ks[buf][w * 512], kSrc + (size_t)tile * 64 * DKH);
    gload16(&Vs[buf][w * 512], vSrc + tile * 64);
  };

  int rot = qb * 2;  // rotated k-start spreads L2 sets across a head's blocks
  stage(0, rot);     // prologue

  bf16x8 qf[2][2];  // [qg][dk-half]
#pragma unroll
  for (int qg = 0; qg < 2; ++qg) {
    const u16* qp = Qb + ((size_t)bh * S_LEN + q0 + qh * 32 + qg * 16 + c) * DKH + g * 8;
    qf[qg][0] = *(const bf16x8*)qp;
    qf[qg][1] = *(const bf16x8*)(qp + 32);
  }
  bf16x8 onesf;
#pragma unroll
  for (int i = 0; i < 8; ++i) onesf[i] = (__bf16)1.0f;

  // precomputed LDS fragment pointers (buf0); buf1 = +4096 u16 (compile-time)
  const u16* kptr[2][2];  // [fm][dk-half]
#pragma unroll
  for (int fm = 0; fm < 2; ++fm) {
    int row = h * 32 + fm * 16 + c;
    kptr[fm][0] = &Ks[0][row * 64 + ((g ^ (row & 7)) * 8)];
    kptr[fm][1] = &Ks[0][row * 64 + (((4 + g) ^ (row & 7)) * 8)];
  }
  const u16* vptr[4];  // [fd]
#pragma unroll
  for (int fd = 0; fd < 4; ++fd) {
    int vrow = fd * 16 + c;
    vptr[fd] = &Vs[0][vrow * 64 + (((4 * h + g) ^ (vrow & 7)) * 8)];
  }

  f32x4 attT[4][2];  // [fd][qg]
#pragma unroll
  for (int i = 0; i < 4; ++i)
#pragma unroll
    for (int qg = 0; qg < 2; ++qg) attT[i][qg] = (f32x4){0.f, 0.f, 0.f, 0.f};
  f32x4 denacc[2];
  denacc[0] = (f32x4){0.f, 0.f, 0.f, 0.f};
  denacc[1] = (f32x4){0.f, 0.f, 0.f, 0.f};

  auto compute = [&](const int off) {  // off: 0 or 4096 (compile-time literal)
    f32x4 sT[2][2];  // [fm][qg]
    __builtin_amdgcn_s_setprio(1);
#pragma unroll
    for (int fm = 0; fm < 2; ++fm) {
      bf16x8 a0 = *(const bf16x8*)(kptr[fm][0] + off);
      bf16x8 a1 = *(const bf16x8*)(kptr[fm][1] + off);
#pragma unroll
      for (int qg = 0; qg < 2; ++qg) {
        f32x4 z = (f32x4){0.f, 0.f, 0.f, 0.f};
        z = __builtin_amdgcn_mfma_f32_16x16x32_bf16(a0, qf[qg][0], z, 0, 0, 0);
        sT[fm][qg] = __builtin_amdgcn_mfma_f32_16x16x32_bf16(a1, qf[qg][1], z, 0, 0, 0);
      }
    }
    __builtin_amdgcn_s_setprio(0);
    u32 wq[2][2][2];  // [qg][fm][r]
#pragma unroll
    for (int fm = 0; fm < 2; ++fm)
#pragma unroll
      for (int qg = 0; qg < 2; ++qg) {
        float pv[4];
#pragma unroll
        for (int j = 0; j < 4; ++j) {
          float cv = __builtin_amdgcn_cosf(sT[fm][qg][j]);  // revolutions
          float w2 = __fmaf_rn(cv, __fmaf_rn(0.2f * L2E, cv, L2E), -0.1f * L2E);
          pv[j] = __builtin_amdgcn_exp2f(w2);
        }
        wq[qg][fm][0] = pk_bf16(pv[0], pv[1]);
        wq[qg][fm][1] = pk_bf16(pv[2], pv[3]);
      }
    bf16x8 pf[2];
#pragma unroll
    for (int qg = 0; qg < 2; ++qg) {
      u32 b0 = wq[qg][0][0], b2 = wq[qg][1][0];
      pl32swap(b0, b2);
      pl16swap(b0, b2);
      u32 b1 = wq[qg][0][1], b3 = wq[qg][1][1];
      pl32swap(b1, b3);
      pl16swap(b1, b3);
      pf[qg] = __builtin_bit_cast(bf16x8, (u32x4){b0, b1, b2, b3});
    }
    __builtin_amdgcn_s_setprio(1);
#pragma unroll
    for (int fd = 0; fd < 4; ++fd) {
      bf16x8 vf = *(const bf16x8*)(vptr[fd] + off);
#pragma unroll
      for (int qg = 0; qg < 2; ++qg)
        attT[fd][qg] = __builtin_amdgcn_mfma_f32_16x16x32_bf16(vf, pf[qg], attT[fd][qg], 0, 0, 0);
    }
#pragma unroll
    for (int qg = 0; qg < 2; ++qg)
      denacc[qg] = __builtin_amdgcn_mfma_f32_16x16x32_bf16(onesf, pf[qg], denacc[qg], 0, 0, 0);
    __builtin_amdgcn_s_setprio(0);
  };

  __syncthreads();
  for (int t = 0; t < 32; t += 2) {
    stage(1, (t + 1 + rot) & 31);
    compute(0);
    __syncthreads();
    if (t + 2 < 32) stage(0, (t + 2 + rot) & 31);
    compute(4096);
    __syncthreads();
  }

  // ---- epilogue: per-group combine of h-partners ----
  if (g == 0) {
    dred[w][0][c] = denacc[0][0];
    dred[w][1][c] = denacc[1][0];
  }
  // 4 disjoint 8KB regions in retired staging LDS: (grp,qh)
  float* Rq = (grp ? (float*)&Vs[0][0] : (float*)&Ks[0][0]) + qh * 2048;
  if (h == 1) {
#pragma unroll
    for (int fd = 0; fd < 4; ++fd)
#pragma unroll
      for (int qg = 0; qg < 2; ++qg)
        *(f32x4*)&Rq[(qg * 16 + c) * 64 + fd * 16 + 4 * g] = attT[fd][qg];
  }
  __syncthreads();
  if (h == 0) {
    float inv[2];
#pragma unroll
    for (int qg = 0; qg < 2; ++qg)
      inv[qg] = 1.f / (dred[w][qg][c] + dred[w ^ 2][qg][c]);
#pragma unroll
    for (int fd = 0; fd < 4; ++fd)
#pragma unroll
      for (int qg = 0; qg < 2; ++qg) {
        f32x4 part = *(const f32x4*)&Rq[(qg * 16 + c) * 64 + fd * 16 + 4 * g];
        f32x4 tot = (attT[fd][qg] + part) * inv[qg];
        int q = q0 + qh * 32 + qg * 16 + c;
        *(f32x4*)(attbuf + ((size_t)bh * S_LEN + q) * DKH + fd * 16 + 4 * g) = tot;
      }
  }
}

// ---------------- head-reduce + a@Wo_eff + bias + residual + LayerNorm ----------------
__global__ __launch_bounds__(256) void fuse_out_ln_k(const float* __restrict__ attbuf,
    const float* __restrict__ Woeff, const float* __restrict__ bo,
    const float* __restrict__ x, const float* __restrict__ gamma,
    const float* __restrict__ beta, float* __restrict__ out) {
  __shared__ float red[8][256];
  __shared__ __align__(16) float a[8][64];
  __shared__ float sred[8][4][2];
  int t = threadIdx.x;
  int r0 = blockIdx.x * 8;
  int d = t & 63, hg = t >> 6;
#pragma unroll
  for (int rr = 0; rr < 8; ++rr) {
    int m = r0 + rr, b = m >> 11, sr = m & 2047;
    float pa = 0.f;
#pragma unroll
    for (int hh = 0; hh < 4; ++hh) {
      int h = hg * 4 + hh;
      pa += attbuf[(((size_t)(b * 16 + h)) * S_LEN + sr) * DKH + d];
    }
    red[rr][t] = pa;
  }
  __syncthreads();
#pragma unroll
  for (int e = 0; e < 2; ++e) {
    int idx = t + e * 256;
    int rr = idx >> 6, dd = idx & 63;
    a[rr][dd] = red[rr][dd] + red[rr][64 + dd] + red[rr][128 + dd] + red[rr][192 + dd];
  }
  __syncthreads();

  float o[8][4];
#pragma unroll
  for (int rr = 0; rr < 8; ++rr) { o[rr][0] = o[rr][1] = o[rr][2] = o[rr][3] = 0.f; }
  int c4 = t * 4;
  for (int dd = 0; dd < 64; dd += 4) {
    float4 wv0 = *(const float4*)(Woeff + (size_t)(dd + 0) * DMODEL + c4);
    float4 wv1 = *(const float4*)(Woeff + (size_t)(dd + 1) * DMODEL + c4);
    float4 wv2 = *(const float4*)(Woeff + (size_t)(dd + 2) * DMODEL + c4);
    float4 wv3 = *(const float4*)(Woeff + (size_t)(dd + 3) * DMODEL + c4);
#pragma unroll
    for (int rr = 0; rr < 8; ++rr) {
      float4 av = *(const float4*)&a[rr][dd];
      o[rr][0] += av.x * wv0.x + av.y * wv1.x + av.z * wv2.x + av.w * wv3.x;
      o[rr][1] += av.x * wv0.y + av.y * wv1.y + av.z * wv2.y + av.w * wv3.y;
      o[rr][2] += av.x * wv0.z + av.y * wv1.z + av.z * wv2.z + av.w * wv3.z;
      o[rr][3] += av.x * wv0.w + av.y * wv1.w + av.z * wv2.w + av.w * wv3.w;
    }
  }
  float4 bv = *(const float4*)(bo + c4);
  int w = t >> 6, lane = t & 63;
#pragma unroll
  for (int rr = 0; rr < 8; ++rr) {
    int m = r0 + rr;
    float4 xv = *(const float4*)(x + (size_t)m * DMODEL + c4);
    o[rr][0] += bv.x + xv.x;
    o[rr][1] += bv.y + xv.y;
    o[rr][2] += bv.z + xv.z;
    o[rr][3] += bv.w + xv.w;
    float s = o[rr][0] + o[rr][1] + o[rr][2] + o[rr][3];
    float q = o[rr][0] * o[rr][0] + o[rr][1] * o[rr][1] + o[rr][2] * o[rr][2] + o[rr][3] * o[rr][3];
#pragma unroll
    for (int mm = 1; mm < 64; mm <<= 1) {
      s += __shfl_xor(s, mm, 64);
      q += __shfl_xor(q, mm, 64);
    }
    if (lane == 0) { sred[rr][w][0] = s; sred[rr][w][1] = q; }
  }
  __syncthreads();
  float4 gv = *(const float4*)(gamma + c4);
  float4 bev = *(const float4*)(beta + c4);
#pragma unroll
  for (int rr = 0; rr < 8; ++rr) {
    float s = sred[rr][0][0] + sred[rr][1][0] + sred[rr][2][0] + sred[rr][3][0];
    float q = sred[rr][0][1] + sred[rr][1][1] + sred[rr][2][1] + sred[rr][3][1];
    float mu = s * (1.f / 1024.f);
    float var = q * (1.f / 1024.f) - mu * mu;
    float rs = rsqrtf(var + 1e-6f);
    int m = r0 + rr;
    float4 ov;
    ov.x = gv.x * (o[rr][0] - mu) * rs + bev.x;
    ov.y = gv.y * (o[rr][1] - mu) * rs + bev.y;
    ov.z = gv.z * (o[rr][2] - mu) * rs + bev.z;
    ov.w = gv.w * (o[rr][3] - mu) * rs + bev.w;
    *(float4*)(out + (size_t)m * DMODEL + c4) = ov;
  }
}

extern "C" void kernel_launch(void* const* d_in, const int* in_sizes, int n_in,
                              void* d_out, int out_size, void* d_ws, size_t ws_size,
                              hipStream_t stream) {
  const float* x = (const float*)d_in[0];
  const float* Wq = (const float*)d_in[1];
  const float* Wk = (const float*)d_in[2];
  const float* Wv = (const float*)d_in[3];
  const float* Wo = (const float*)d_in[4];
  const float* bo = (const float*)d_in[5];
  const float* ps = (const float*)d_in[6];
  const float* ent = (const float*)d_in[7];
  const float* gamma = (const float*)d_in[8];
  const float* beta = (const float*)d_in[9];
  float* out = (float*)d_out;

  char* ws = (char*)d_ws;
  size_t o = 0;
  u16* xb = (u16*)(ws + o);    o += (size_t)MROWS * DMODEL * 2;        // 8 MB
  u16* Wb = (u16*)(ws + o);    o += (size_t)3072 * 1024 * 2;           // 6 MB
  u16* Qb = (u16*)(ws + o);    o += (size_t)BH_CNT * S_LEN * DKH * 2;  // 8 MB
  u16* Kb = (u16*)(ws + o);    o += (size_t)BH_CNT * S_LEN * DKH * 2;  // 8 MB
  u16* Vt = (u16*)(ws + o);    o += (size_t)BH_CNT * S_LEN * DKH * 2;  // 8 MB
  float* Woeff = (float*)(ws + o);  o += (size_t)DKH * DMODEL * 4;     // 256 KB
  float* attbuf = (float*)(ws + o); o += (size_t)BH_CNT * S_LEN * DKH * 4;  // 16 MB

  prep_xb_k<<<dim3(4096), dim3(256), 0, stream>>>(x, xb);
  prep_w_k<<<dim3(32, 32, 3), dim3(32, 8), 0, stream>>>(Wq, Wk, Wv, ps, Wb);
  prep_woeff_k<<<dim3(256), dim3(256), 0, stream>>>(Wo, ent, Woeff);
  gemm_qkv_k<<<dim3(768), dim3(256), 0, stream>>>(xb, Wb, Qb, Kb, Vt);
  attn_k<<<dim3(512), dim3(512), 0, stream>>>(Qb, Kb, Vt, attbuf);
  fuse_out_ln_k<<<dim3(512), dim3(256), 0, stream>>>(attbuf, Woeff, bo, x, gamma, beta, out);
}

// Round 12
// 123.665 us; speedup vs baseline: 1.3191x; 1.0431x over previous
//
#include <hip/hip_runtime.h>
#include <cstdint>
#include <cstddef>

#define S_LEN 2048
#define DMODEL 1024
#define NHEADS 16
#define DKH 64
#define MROWS 4096
#define BH_CNT 32

typedef __bf16 bf16x8 __attribute__((ext_vector_type(8)));
typedef __bf16 bf16x2 __attribute__((ext_vector_type(2)));
typedef float f32x4 __attribute__((ext_vector_type(4)));
typedef unsigned int u32x4 __attribute__((ext_vector_type(4)));
typedef unsigned int u32;
typedef unsigned short u16;

__device__ __forceinline__ u16 f2bfu(float f) {
  u32 u = __float_as_uint(f);
  return (u16)((u + 0x7FFFu + ((u >> 16) & 1u)) >> 16);
}

__device__ __forceinline__ float bf2f(u16 v) {
  return __uint_as_float((u32)v << 16);
}

// compiler-cast bf16 pack (lowers to v_cvt_pk_bf16_f32 on gfx950)
__device__ __forceinline__ u32 pk_bf16(float a, float b) {
  bf16x2 v;
  v[0] = (__bf16)a;
  v[1] = (__bf16)b;
  return __builtin_bit_cast(u32, v);
}

// true-swap cross-lane ops (gfx950): both operands modified
__device__ __forceinline__ void pl32swap(u32& a, u32& b) {
#if __has_builtin(__builtin_amdgcn_permlane32_swap)
  auto r = __builtin_amdgcn_permlane32_swap((int)a, (int)b, false, false);
  a = (u32)r[0]; b = (u32)r[1];
#else
  asm volatile("v_permlane32_swap_b32 %0, %1" : "+v"(a), "+v"(b));
#endif
}
__device__ __forceinline__ void pl16swap(u32& a, u32& b) {
#if __has_builtin(__builtin_amdgcn_permlane16_swap)
  auto r = __builtin_amdgcn_permlane16_swap((int)a, (int)b, false, false);
  a = (u32)r[0]; b = (u32)r[1];
#else
  asm volatile("v_permlane16_swap_b32 %0, %1" : "+v"(a), "+v"(b));
#endif
}

__device__ __forceinline__ void gload16(void* lds, const void* g) {
  __builtin_amdgcn_global_load_lds(
      (const __attribute__((address_space(1))) void*)g,
      (__attribute__((address_space(3))) void*)lds, 16, 0, 0);
}

// ---------------- merged prep: x->bf16 | W^T bf16 (K pre-scaled) | Wo_eff ----------------
// blocks [0,4096): x cast; [4096,7168): W transpose; [7168,7424): Wo_eff.
// K scale folds 1/sqrt(dk)*phase AND 1/(2pi): scores arrive in REVOLUTIONS.
__global__ __launch_bounds__(256) void prep_all_k(const float* __restrict__ x,
    const float* __restrict__ Wq, const float* __restrict__ Wk,
    const float* __restrict__ Wv, const float* __restrict__ Wo,
    const float* __restrict__ ps, const float* __restrict__ ent,
    u16* __restrict__ xb, u16* __restrict__ Wb, float* __restrict__ Woeff) {
  __shared__ float tile[32][33];
  int bid = blockIdx.x;
  int t = threadIdx.x;
  if (bid < 4096) {
    int i = (bid * 256 + t) * 4;
    float4 v = *(const float4*)(x + i);
    *(uint2*)(xb + i) = make_uint2(pk_bf16(v.x, v.y), pk_bf16(v.z, v.w));
  } else if (bid < 7168) {
    int lb = bid - 4096;
    int sel = lb >> 10, rem = lb & 1023;
    int k0 = (rem & 31) * 32, c0 = (rem >> 5) * 32;
    const float* W = sel == 0 ? Wq : (sel == 1 ? Wk : Wv);
    int tx = t & 31, ty = t >> 5;
#pragma unroll
    for (int i = 0; i < 4; ++i)
      tile[ty + i * 8][tx] = W[(size_t)(k0 + ty + i * 8) * DMODEL + c0 + tx];
    __syncthreads();
#pragma unroll
    for (int i = 0; i < 4; ++i) {
      int row = ty + i * 8;
      float v = tile[tx][row];
      if (sel == 1) v *= 0.019894367886486918f * ps[(c0 + row) >> 6];  // 0.125/(2pi)
      Wb[(size_t)(sel * 1024 + c0 + row) * DMODEL + k0 + tx] = f2bfu(v);
    }
  } else {
    __shared__ float e[16];
    if (t < 16) {
      float s = 0.f;
#pragma unroll
      for (int h = 0; h < 16; ++h) s += ent[h * 16 + t];
      e[t] = s;
    }
    __syncthreads();
    int gid = (bid - 7168) * 256 + t;
    int d = gid >> 10, j = gid & 1023;
    float acc = 0.f;
#pragma unroll
    for (int m = 0; m < 16; ++m) acc += e[m] * Wo[(size_t)((m << 6) + d) * DMODEL + j];
    Woeff[(size_t)d * DMODEL + j] = acc;
  }
}

// ---------------- QKV projection GEMM: [4096,1024] x [1024,3072] ----------------
// 128x128 tile, BK=32, double-buffered staging, one barrier per K-step.
// Grid: XCD-rectangle swizzle. Epilogue through LDS for coalesced stores.
__global__ __launch_bounds__(256) void gemm_qkv_k(const u16* __restrict__ xb,
    const u16* __restrict__ Wb, u16* __restrict__ Qb, u16* __restrict__ Kb,
    u16* __restrict__ Vt) {
  __shared__ __align__(16) u16 SMEM[2][2][128 * 32];  // [A/B][dbuf][tile]
  int bid = blockIdx.x;
  int xcd = bid & 7, wi = bid >> 3;
  int mg = xcd >> 1, ng = xcd & 1;
  int mt = mg * 8 + (wi & 7);
  int nt = ng * 12 + (wi >> 3);
  int m0 = mt * 128, n0 = nt * 128;
  int tid = threadIdx.x;
  int lane = tid & 63, w = tid >> 6;
  int c = lane & 15, g = lane >> 4;
  int wr = w >> 1, wc = w & 1;

  int cij0 = (w * 2) * 64 + lane, cij1 = (w * 2 + 1) * 64 + lane;
  int row0 = cij0 >> 2, kp0 = (cij0 & 3) ^ (row0 & 3);
  int row1 = cij1 >> 2, kp1 = (cij1 & 3) ^ (row1 & 3);
  const u16* a0p = xb + (size_t)(m0 + row0) * DMODEL + kp0 * 8;
  const u16* a1p = xb + (size_t)(m0 + row1) * DMODEL + kp1 * 8;
  const u16* b0p = Wb + (size_t)(n0 + row0) * DMODEL + kp0 * 8;
  const u16* b1p = Wb + (size_t)(n0 + row1) * DMODEL + kp1 * 8;

  f32x4 acc[4][4];
#pragma unroll
  for (int i = 0; i < 4; ++i)
#pragma unroll
    for (int j = 0; j < 4; ++j) acc[i][j] = (f32x4){0.f, 0.f, 0.f, 0.f};

  // prologue stage
  gload16(&SMEM[0][0][(w * 2) * 512], a0p);
  gload16(&SMEM[0][0][(w * 2 + 1) * 512], a1p);
  gload16(&SMEM[1][0][(w * 2) * 512], b0p);
  gload16(&SMEM[1][0][(w * 2 + 1) * 512], b1p);
  __syncthreads();

  int cur = 0;
  for (int kt = 0; kt < DMODEL; kt += 32) {
    if (kt + 32 < DMODEL) {
      int nx = cur ^ 1, ko = kt + 32;
      gload16(&SMEM[0][nx][(w * 2) * 512], a0p + ko);
      gload16(&SMEM[0][nx][(w * 2 + 1) * 512], a1p + ko);
      gload16(&SMEM[1][nx][(w * 2) * 512], b0p + ko);
      gload16(&SMEM[1][nx][(w * 2 + 1) * 512], b1p + ko);
    }
    const u16* Ac = SMEM[0][cur];
    const u16* Bc = SMEM[1][cur];
    bf16x8 af[4], bf[4];
#pragma unroll
    for (int i = 0; i < 4; ++i) {
      int ra = wr * 64 + i * 16 + c;
      af[i] = *(const bf16x8*)(Ac + ra * 32 + ((g ^ (ra & 3)) * 8));
      int rb = wc * 64 + i * 16 + c;
      bf[i] = *(const bf16x8*)(Bc + rb * 32 + ((g ^ (rb & 3)) * 8));
    }
#pragma unroll
    for (int i = 0; i < 4; ++i)
#pragma unroll
      for (int j = 0; j < 4; ++j)
        acc[i][j] = __builtin_amdgcn_mfma_f32_16x16x32_bf16(af[i], bf[j], acc[i][j], 0, 0, 0);
    __syncthreads();
    cur ^= 1;
  }

  // ---- epilogue via LDS (reuse staging buffers: 32KB = 128x128 u16) ----
  int sel = n0 >> 10;
  char* Ls = (char*)&SMEM[0][0][0];
  if (sel == 2) {
    // LDS layout transposed: row = n-local (d), col = m-local (s)
#pragma unroll
    for (int i = 0; i < 4; ++i)
#pragma unroll
      for (int jf = 0; jf < 4; ++jf) {
        int n = wc * 64 + jf * 16 + c;
        int m = wr * 64 + i * 16 + 4 * g;
        int byte = n * 256 + ((m * 2) ^ ((n & 7) << 4));
        *(uint2*)(Ls + byte) = make_uint2(pk_bf16(acc[i][jf][0], acc[i][jf][1]),
                                          pk_bf16(acc[i][jf][2], acc[i][jf][3]));
      }
  } else {
    // LDS layout: row = m-local (s), col = n-local (d)
#pragma unroll
    for (int i = 0; i < 4; ++i)
#pragma unroll
      for (int jf = 0; jf < 4; ++jf) {
        int n = wc * 64 + jf * 16 + c;
#pragma unroll
        for (int j = 0; j < 4; ++j) {
          int m = wr * 64 + i * 16 + 4 * g + j;
          int byte = m * 256 + ((n * 2) ^ ((m & 7) << 4));
          __bf16 hv = (__bf16)acc[i][jf][j];
          *(u16*)(Ls + byte) = __builtin_bit_cast(u16, hv);
        }
      }
  }
  __syncthreads();
  int r = tid >> 1, half = tid & 1;
  int h0 = (n0 & 1023) >> 6;
  int b = m0 >> 11, sbase = m0 & 2047;
  u16* dst;
  if (sel == 2) {
    int bh = b * 16 + h0 + (r >> 6), d = r & 63;
    dst = Vt + ((size_t)bh * DKH + d) * S_LEN + sbase + half * 64;
  } else {
    u16* base = (sel == 0 ? Qb : Kb);
    int bh = b * 16 + h0 + half;
    dst = base + ((size_t)bh * S_LEN + sbase + r) * DKH;
  }
#pragma unroll
  for (int kk = 0; kk < 8; ++kk) {
    int byte = r * 256 + ((half * 128 + kk * 16) ^ ((r & 7) << 4));
    *(uint4*)(dst + kk * 8) = *(const uint4*)(Ls + byte);
  }
}

// ---------------- fused cos-softmax flash attention ----------------
// 8 waves / 512 threads (grp x h x qh), one shared staged K/V tile per block.
// QUAD-buffered staging: 2 tiles staged per phase, 2 computed between
// barriers -> 16 barrier-drain events per block (vs 32). Compute recipe
// verified since round 7: S^T = mfma(K,Q); in-register softmax (v_cos +
// 2 fma + v_exp2, scores in revolutions); permlane32/16 swaps move P into
// the PV B-fragment; denominator via ones-row MFMA. Output written as bf16.
__global__ __launch_bounds__(512) void attn_k(const u16* __restrict__ Qb,
    const u16* __restrict__ Kb, const u16* __restrict__ Vt,
    u16* __restrict__ attbufb) {
  __shared__ __align__(16) u16 Ks[4][4096];  // [4buf][64x64] = 32KB
  __shared__ __align__(16) u16 Vs[4][4096];  // [4buf][64x64] = 32KB
  __shared__ float dred[8][2][16];
  int fid = blockIdx.x;
  int swz = (fid & 7) * 64 + (fid >> 3);  // 512 blocks, 8 XCDs -> bijective
  int bh = swz >> 4, qb = swz & 15;       // 4 heads per XCD (K/V 2MB L2-resident)
  int tid = threadIdx.x;
  int lane = tid & 63, w = tid >> 6;
  int c = lane & 15, g = lane >> 4;
  int grp = w >> 2, h = (w >> 1) & 1, qh = w & 1;
  int q0 = qb * 128 + grp * 64;
  const float L2E = 1.4426950408889634f;

  const u16* Kbase = Kb + (size_t)bh * S_LEN * DKH;
  const u16* Vbase = Vt + (size_t)bh * DKH * S_LEN;

  // staging: wave w stages chunk w (512 u16) of Ks and Vs (pre-swizzled src)
  int srow = w * 8 + (lane >> 3), slot = lane & 7, kp = slot ^ (srow & 7);
  const u16* kSrc = Kbase + (size_t)srow * DKH + kp * 8;
  const u16* vSrc = Vbase + (size_t)srow * S_LEN + kp * 8;
  auto stage = [&](int buf, int tile) {
    gload16(&Ks[buf][w * 512], kSrc + (size_t)tile * 64 * DKH);
    gload16(&Vs[buf][w * 512], vSrc + tile * 64);
  };

  int rot = qb * 2;  // rotated k-start spreads L2 sets across a head's blocks
  stage(0, rot & 31);
  stage(1, (rot + 1) & 31);

  bf16x8 qf[2][2];  // [qg][dk-half]
#pragma unroll
  for (int qg = 0; qg < 2; ++qg) {
    const u16* qp = Qb + ((size_t)bh * S_LEN + q0 + qh * 32 + qg * 16 + c) * DKH + g * 8;
    qf[qg][0] = *(const bf16x8*)qp;
    qf[qg][1] = *(const bf16x8*)(qp + 32);
  }
  bf16x8 onesf;
#pragma unroll
  for (int i = 0; i < 8; ++i) onesf[i] = (__bf16)1.0f;

  // precomputed LDS fragment pointers (buf0); bufN = +N*4096 u16 (compile-time)
  const u16* kptr[2][2];  // [fm][dk-half]
#pragma unroll
  for (int fm = 0; fm < 2; ++fm) {
    int row = h * 32 + fm * 16 + c;
    kptr[fm][0] = &Ks[0][row * 64 + ((g ^ (row & 7)) * 8)];
    kptr[fm][1] = &Ks[0][row * 64 + (((4 + g) ^ (row & 7)) * 8)];
  }
  const u16* vptr[4];  // [fd]
#pragma unroll
  for (int fd = 0; fd < 4; ++fd) {
    int vrow = fd * 16 + c;
    vptr[fd] = &Vs[0][vrow * 64 + (((4 * h + g) ^ (vrow & 7)) * 8)];
  }

  f32x4 attT[4][2];  // [fd][qg]
#pragma unroll
  for (int i = 0; i < 4; ++i)
#pragma unroll
    for (int qg = 0; qg < 2; ++qg) attT[i][qg] = (f32x4){0.f, 0.f, 0.f, 0.f};
  f32x4 denacc[2];
  denacc[0] = (f32x4){0.f, 0.f, 0.f, 0.f};
  denacc[1] = (f32x4){0.f, 0.f, 0.f, 0.f};

  auto compute = [&](const int off) {  // off: buf*4096 (compile-time literal)
    f32x4 sT[2][2];  // [fm][qg]
    __builtin_amdgcn_s_setprio(1);
#pragma unroll
    for (int fm = 0; fm < 2; ++fm) {
      bf16x8 a0 = *(const bf16x8*)(kptr[fm][0] + off);
      bf16x8 a1 = *(const bf16x8*)(kptr[fm][1] + off);
#pragma unroll
      for (int qg = 0; qg < 2; ++qg) {
        f32x4 z = (f32x4){0.f, 0.f, 0.f, 0.f};
        z = __builtin_amdgcn_mfma_f32_16x16x32_bf16(a0, qf[qg][0], z, 0, 0, 0);
        sT[fm][qg] = __builtin_amdgcn_mfma_f32_16x16x32_bf16(a1, qf[qg][1], z, 0, 0, 0);
      }
    }
    __builtin_amdgcn_s_setprio(0);
    u32 wq[2][2][2];  // [qg][fm][r]
#pragma unroll
    for (int fm = 0; fm < 2; ++fm)
#pragma unroll
      for (int qg = 0; qg < 2; ++qg) {
        float pv[4];
#pragma unroll
        for (int j = 0; j < 4; ++j) {
          float cv = __builtin_amdgcn_cosf(sT[fm][qg][j]);  // revolutions
          float w2 = __fmaf_rn(cv, __fmaf_rn(0.2f * L2E, cv, L2E), -0.1f * L2E);
          pv[j] = __builtin_amdgcn_exp2f(w2);
        }
        wq[qg][fm][0] = pk_bf16(pv[0], pv[1]);
        wq[qg][fm][1] = pk_bf16(pv[2], pv[3]);
      }
    bf16x8 pf[2];
#pragma unroll
    for (int qg = 0; qg < 2; ++qg) {
      u32 b0 = wq[qg][0][0], b2 = wq[qg][1][0];
      pl32swap(b0, b2);
      pl16swap(b0, b2);
      u32 b1 = wq[qg][0][1], b3 = wq[qg][1][1];
      pl32swap(b1, b3);
      pl16swap(b1, b3);
      pf[qg] = __builtin_bit_cast(bf16x8, (u32x4){b0, b1, b2, b3});
    }
    __builtin_amdgcn_s_setprio(1);
#pragma unroll
    for (int fd = 0; fd < 4; ++fd) {
      bf16x8 vf = *(const bf16x8*)(vptr[fd] + off);
#pragma unroll
      for (int qg = 0; qg < 2; ++qg)
        attT[fd][qg] = __builtin_amdgcn_mfma_f32_16x16x32_bf16(vf, pf[qg], attT[fd][qg], 0, 0, 0);
    }
#pragma unroll
    for (int qg = 0; qg < 2; ++qg)
      denacc[qg] = __builtin_amdgcn_mfma_f32_16x16x32_bf16(onesf, pf[qg], denacc[qg], 0, 0, 0);
    __builtin_amdgcn_s_setprio(0);
  };

  __syncthreads();
  for (int t = 0; t < 32; t += 4) {
    stage(2, (t + 2 + rot) & 31);
    stage(3, (t + 3 + rot) & 31);
    compute(0);
    compute(4096);
    __syncthreads();
    if (t + 4 < 32) {
      stage(0, (t + 4 + rot) & 31);
      stage(1, (t + 5 + rot) & 31);
    }
    compute(8192);
    compute(12288);
    __syncthreads();
  }

  // ---- epilogue: per-group combine of h-partners, bf16 store ----
  if (g == 0) {
    dred[w][0][c] = denacc[0][0];
    dred[w][1][c] = denacc[1][0];
  }
  // 4 disjoint 8KB regions in retired staging LDS: (grp,qh)
  float* Rq = (grp ? (float*)&Vs[0][0] : (float*)&Ks[0][0]) + qh * 2048;
  if (h == 1) {
#pragma unroll
    for (int fd = 0; fd < 4; ++fd)
#pragma unroll
      for (int qg = 0; qg < 2; ++qg)
        *(f32x4*)&Rq[(qg * 16 + c) * 64 + fd * 16 + 4 * g] = attT[fd][qg];
  }
  __syncthreads();
  if (h == 0) {
    float inv[2];
#pragma unroll
    for (int qg = 0; qg < 2; ++qg)
      inv[qg] = 1.f / (dred[w][qg][c] + dred[w ^ 2][qg][c]);
#pragma unroll
    for (int fd = 0; fd < 4; ++fd)
#pragma unroll
      for (int qg = 0; qg < 2; ++qg) {
        f32x4 part = *(const f32x4*)&Rq[(qg * 16 + c) * 64 + fd * 16 + 4 * g];
        f32x4 tot = (attT[fd][qg] + part) * inv[qg];
        int q = q0 + qh * 32 + qg * 16 + c;
        *(uint2*)(attbufb + ((size_t)bh * S_LEN + q) * DKH + fd * 16 + 4 * g) =
            make_uint2(pk_bf16(tot[0], tot[1]), pk_bf16(tot[2], tot[3]));
      }
  }
}

// ---------------- head-reduce + a@Wo_eff + bias + residual + LayerNorm ----------------
__global__ __launch_bounds__(256) void fuse_out_ln_k(const u16* __restrict__ attbufb,
    const float* __restrict__ Woeff, const float* __restrict__ bo,
    const float* __restrict__ x, const float* __restrict__ gamma,
    const float* __restrict__ beta, float* __restrict__ out) {
  __shared__ float red[8][256];
  __shared__ __align__(16) float a[8][64];
  __shared__ float sred[8][4][2];
  int t = threadIdx.x;
  int r0 = blockIdx.x * 8;
  int d = t & 63, hg = t >> 6;
#pragma unroll
  for (int rr = 0; rr < 8; ++rr) {
    int m = r0 + rr, b = m >> 11, sr = m & 2047;
    float pa = 0.f;
#pragma unroll
    for (int hh = 0; hh < 4; ++hh) {
      int h = hg * 4 + hh;
      pa += bf2f(attbufb[(((size_t)(b * 16 + h)) * S_LEN + sr) * DKH + d]);
    }
    red[rr][t] = pa;
  }
  __syncthreads();
#pragma unroll
  for (int e = 0; e < 2; ++e) {
    int idx = t + e * 256;
    int rr = idx >> 6, dd = idx & 63;
    a[rr][dd] = red[rr][dd] + red[rr][64 + dd] + red[rr][128 + dd] + red[rr][192 + dd];
  }
  __syncthreads();

  float o[8][4];
#pragma unroll
  for (int rr = 0; rr < 8; ++rr) { o[rr][0] = o[rr][1] = o[rr][2] = o[rr][3] = 0.f; }
  int c4 = t * 4;
  for (int dd = 0; dd < 64; dd += 4) {
    float4 wv0 = *(const float4*)(Woeff + (size_t)(dd + 0) * DMODEL + c4);
    float4 wv1 = *(const float4*)(Woeff + (size_t)(dd + 1) * DMODEL + c4);
    float4 wv2 = *(const float4*)(Woeff + (size_t)(dd + 2) * DMODEL + c4);
    float4 wv3 = *(const float4*)(Woeff + (size_t)(dd + 3) * DMODEL + c4);
#pragma unroll
    for (int rr = 0; rr < 8; ++rr) {
      float4 av = *(const float4*)&a[rr][dd];
      o[rr][0] += av.x * wv0.x + av.y * wv1.x + av.z * wv2.x + av.w * wv3.x;
      o[rr][1] += av.x * wv0.y + av.y * wv1.y + av.z * wv2.y + av.w * wv3.y;
      o[rr][2] += av.x * wv0.z + av.y * wv1.z + av.z * wv2.z + av.w * wv3.z;
      o[rr][3] += av.x * wv0.w + av.y * wv1.w + av.z * wv2.w + av.w * wv3.w;
    }
  }
  float4 bv = *(const float4*)(bo + c4);
  int w = t >> 6, lane = t & 63;
#pragma unroll
  for (int rr = 0; rr < 8; ++rr) {
    int m = r0 + rr;
    float4 xv = *(const float4*)(x + (size_t)m * DMODEL + c4);
    o[rr][0] += bv.x + xv.x;
    o[rr][1] += bv.y + xv.y;
    o[rr][2] += bv.z + xv.z;
    o[rr][3] += bv.w + xv.w;
    float s = o[rr][0] + o[rr][1] + o[rr][2] + o[rr][3];
    float q = o[rr][0] * o[rr][0] + o[rr][1] * o[rr][1] + o[rr][2] * o[rr][2] + o[rr][3] * o[rr][3];
#pragma unroll
    for (int mm = 1; mm < 64; mm <<= 1) {
      s += __shfl_xor(s, mm, 64);
      q += __shfl_xor(q, mm, 64);
    }
    if (lane == 0) { sred[rr][w][0] = s; sred[rr][w][1] = q; }
  }
  __syncthreads();
  float4 gv = *(const float4*)(gamma + c4);
  float4 bev = *(const float4*)(beta + c4);
#pragma unroll
  for (int rr = 0; rr < 8; ++rr) {
    float s = sred[rr][0][0] + sred[rr][1][0] + sred[rr][2][0] + sred[rr][3][0];
    float q = sred[rr][0][1] + sred[rr][1][1] + sred[rr][2][1] + sred[rr][3][1];
    float mu = s * (1.f / 1024.f);
    float var = q * (1.f / 1024.f) - mu * mu;
    float rs = rsqrtf(var + 1e-6f);
    int m = r0 + rr;
    float4 ov;
    ov.x = gv.x * (o[rr][0] - mu) * rs + bev.x;
    ov.y = gv.y * (o[rr][1] - mu) * rs + bev.y;
    ov.z = gv.z * (o[rr][2] - mu) * rs + bev.z;
    ov.w = gv.w * (o[rr][3] - mu) * rs + bev.w;
    *(float4*)(out + (size_t)m * DMODEL + c4) = ov;
  }
}

extern "C" void kernel_launch(void* const* d_in, const int* in_sizes, int n_in,
                              void* d_out, int out_size, void* d_ws, size_t ws_size,
                              hipStream_t stream) {
  const float* x = (const float*)d_in[0];
  const float* Wq = (const float*)d_in[1];
  const float* Wk = (const float*)d_in[2];
  const float* Wv = (const float*)d_in[3];
  const float* Wo = (const float*)d_in[4];
  const float* bo = (const float*)d_in[5];
  const float* ps = (const float*)d_in[6];
  const float* ent = (const float*)d_in[7];
  const float* gamma = (const float*)d_in[8];
  const float* beta = (const float*)d_in[9];
  float* out = (float*)d_out;

  char* ws = (char*)d_ws;
  size_t o = 0;
  u16* xb = (u16*)(ws + o);    o += (size_t)MROWS * DMODEL * 2;        // 8 MB
  u16* Wb = (u16*)(ws + o);    o += (size_t)3072 * 1024 * 2;           // 6 MB
  u16* Qb = (u16*)(ws + o);    o += (size_t)BH_CNT * S_LEN * DKH * 2;  // 8 MB
  u16* Kb = (u16*)(ws + o);    o += (size_t)BH_CNT * S_LEN * DKH * 2;  // 8 MB
  u16* Vt = (u16*)(ws + o);    o += (size_t)BH_CNT * S_LEN * DKH * 2;  // 8 MB
  float* Woeff = (float*)(ws + o);   o += (size_t)DKH * DMODEL * 4;    // 256 KB
  u16* attbufb = (u16*)(ws + o);     o += (size_t)BH_CNT * S_LEN * DKH * 2;  // 8 MB

  prep_all_k<<<dim3(7424), dim3(256), 0, stream>>>(x, Wq, Wk, Wv, Wo, ps, ent,
                                                   xb, Wb, Woeff);
  gemm_qkv_k<<<dim3(768), dim3(256), 0, stream>>>(xb, Wb, Qb, Kb, Vt);
  attn_k<<<dim3(512), dim3(512), 0, stream>>>(Qb, Kb, Vt, attbufb);
  fuse_out_ln_k<<<dim3(512), dim3(256), 0, stream>>>(attbufb, Woeff, bo, x, gamma, beta, out);
}